// Round 10
// baseline (416.807 us; speedup 1.0000x reference)
//
#include <hip/hip_runtime.h>

#define IN_CH 128
#define HIDDEN 64

// ================= CSR build: two-level LDS-binned counting sort ============
// bucket = col >> 8 (256-node ranges). Packed record (row<<8 | col&255) fits
// 32 bits since row < 2^17 for N=100k. Avoids the 16x write-amplification of
// a direct random 4B scatter (R2 profile: fill_kernel wrote 105MB for 6.4MB).

__global__ __launch_bounds__(512)
void bucket_hist_kernel(const int* __restrict__ col, int* __restrict__ bhist, int E) {
    __shared__ int h[512];
    h[threadIdx.x] = 0;
    __syncthreads();
    const int start = blockIdx.x * 8192;
    const int end = min(start + 8192, E);
    for (int e = start + threadIdx.x; e < end; e += 512)
        atomicAdd(&h[col[e] >> 8], 1);
    __syncthreads();
    if (h[threadIdx.x]) atomicAdd(&bhist[threadIdx.x], h[threadIdx.x]);
}

__global__ __launch_bounds__(512)
void bucket_scan_kernel(const int* __restrict__ bhist, int* __restrict__ bbase,
                        int* __restrict__ bpos, int* __restrict__ off,
                        int nb, int N, int E) {
    __shared__ int s[512];
    const int t = threadIdx.x;
    const int v = (t < nb) ? bhist[t] : 0;
    s[t] = v;
    __syncthreads();
    for (int d = 1; d < 512; d <<= 1) {
        int u = (t >= d) ? s[t - d] : 0;
        __syncthreads();
        s[t] += u;
        __syncthreads();
    }
    const int b = s[t] - v;   // exclusive
    if (t < nb) { bbase[t] = b; bpos[t] = b; }
    if (t == 0) { bbase[nb] = E; off[N] = E; }
}

__global__ __launch_bounds__(512)
void bucket_scatter_kernel(const int* __restrict__ row, const int* __restrict__ col,
                           int* __restrict__ bpos, unsigned* __restrict__ tmp, int E) {
    __shared__ int h[512];
    __shared__ int base[512];
    h[threadIdx.x] = 0;
    __syncthreads();
    const int start = blockIdx.x * 8192;
    const int end = min(start + 8192, E);
    for (int e = start + threadIdx.x; e < end; e += 512)
        atomicAdd(&h[col[e] >> 8], 1);
    __syncthreads();
    const int i = threadIdx.x;
    base[i] = h[i] ? atomicAdd(&bpos[i], h[i]) : 0;
    h[i] = 0;
    __syncthreads();
    for (int e = start + threadIdx.x; e < end; e += 512) {
        const int c = col[e];
        const int bk = c >> 8;
        const int p = base[bk] + atomicAdd(&h[bk], 1);
        tmp[p] = ((unsigned)row[e] << 8) | (unsigned)(c & 255);
    }
}

__global__ __launch_bounds__(256)
void bucket_sort_kernel(const unsigned* __restrict__ tmp, const int* __restrict__ bbase,
                        int* __restrict__ off, float* __restrict__ dinv,
                        int* __restrict__ srcrow, int N) {
    __shared__ int cnt[256];
    __shared__ int sc[256];
    const int b = blockIdx.x;
    const int node0 = b << 8;
    const int t = threadIdx.x;
    const int lo = bbase[b], hi = bbase[b + 1];
    cnt[t] = 0;
    __syncthreads();
    for (int j = lo + t; j < hi; j += 256)
        atomicAdd(&cnt[tmp[j] & 255u], 1);
    __syncthreads();
    const int v = cnt[t];
    sc[t] = v;
    __syncthreads();
    for (int d = 1; d < 256; d <<= 1) {
        int u = (t >= d) ? sc[t - d] : 0;
        __syncthreads();
        sc[t] += u;
        __syncthreads();
    }
    const int excl = sc[t] - v;
    const int node = node0 + t;
    if (node < N) {
        off[node] = lo + excl;
        dinv[node] = rsqrtf((float)v + 1.0f);   // deg = 1 (self-loop) + in-degree
    }
    cnt[t] = lo + excl;   // reuse as running write cursor
    __syncthreads();
    for (int j = lo + t; j < hi; j += 256) {
        const unsigned pk = tmp[j];
        const int p = atomicAdd(&cnt[pk & 255u], 1);
        srcrow[p] = (int)(pk >> 8);
    }
}

// ---------------- tiled fp32 GEMM: Hs[N,64] = (X[N,K] @ W[K,64]) * dinv[n] ---

template <int K>
__global__ __launch_bounds__(256)
void gemm_kernel(const float* __restrict__ X, const float* __restrict__ W,
                 const float* __restrict__ dinv, float* __restrict__ Hs, int N) {
    constexpr int BK = 16;
    __shared__ float xs[BK][64];
    __shared__ float ws[BK][64];
    const int tid  = threadIdx.x;
    const int row0 = blockIdx.x * 64;
    const int tx4  = (tid & 15) << 2;
    const int ty4  = (tid >> 4) << 2;
    const int lrow = tid >> 2;
    const int kq   = (tid & 3) << 2;
    const int wk   = tid >> 4;
    const int wc   = (tid & 15) << 2;
    int grow = row0 + lrow;
    if (grow >= N) grow = N - 1;

    float acc[4][4] = {};
    for (int k0 = 0; k0 < K; k0 += BK) {
        const float4 xv = *reinterpret_cast<const float4*>(&X[(size_t)grow * K + k0 + kq]);
        const float4 wv = *reinterpret_cast<const float4*>(&W[(size_t)(k0 + wk) * 64 + wc]);
        __syncthreads();
        xs[kq + 0][lrow] = xv.x;
        xs[kq + 1][lrow] = xv.y;
        xs[kq + 2][lrow] = xv.z;
        xs[kq + 3][lrow] = xv.w;
        *reinterpret_cast<float4*>(&ws[wk][wc]) = wv;
        __syncthreads();
#pragma unroll
        for (int k = 0; k < BK; ++k) {
            const float4 a = *reinterpret_cast<const float4*>(&xs[k][ty4]);
            const float4 b = *reinterpret_cast<const float4*>(&ws[k][tx4]);
            const float av[4] = {a.x, a.y, a.z, a.w};
            const float bv[4] = {b.x, b.y, b.z, b.w};
#pragma unroll
            for (int r = 0; r < 4; ++r)
#pragma unroll
                for (int c = 0; c < 4; ++c)
                    acc[r][c] = fmaf(av[r], bv[c], acc[r][c]);
        }
    }
#pragma unroll
    for (int r = 0; r < 4; ++r) {
        int n = row0 + ty4 + r;
        if (n < N) {
            const float dn = dinv[n];
            float4 v = make_float4(acc[r][0] * dn, acc[r][1] * dn,
                                   acc[r][2] * dn, acc[r][3] * dn);
            *reinterpret_cast<float4*>(&Hs[(size_t)n * 64 + tx4]) = v;
        }
    }
}

// ---------------- pull-style aggregation, fused self-term + bias (+ReLU) ----
// 4 nodes per wave via float4 lanes: quarter-wave (16 lanes) per node,
// 4 feats/lane. One gather instruction fetches FOUR 256B rows (16B/lane) --
// 2x fewer VMEM instructions & addresses per byte than R9's float2 version
// (R9 counters: fill 3.5TB/s, VALU 36%, occ 67% -> request-rate suspected).

template <bool RELU>
__global__ __launch_bounds__(256)
void gather_kernel(const float* __restrict__ Hs, const float* __restrict__ dinv,
                   const int* __restrict__ off, const int* __restrict__ srcrow,
                   const float* __restrict__ bias, float* __restrict__ A, int N) {
    const int tid  = threadIdx.x;
    const int lane = tid & 63;
    const int q    = lane >> 4;              // quarter 0..3 = node sub-id
    const int fl   = (lane & 15) << 2;       // feature base (0,4,...,60)
    const int wid  = tid >> 6;               // wave 0..3
    const int c    = blockIdx.x * 16 + wid * 4 + q;
    const int cc   = (c < N) ? c : N - 1;    // clamp; store is guarded
    const int lo = off[cc], hi = off[cc + 1];

    float4 acc = make_float4(0.f, 0.f, 0.f, 0.f);
    int j = lo;
    while (__any(j < hi)) {
        int idx[8];
#pragma unroll
        for (int u = 0; u < 8; ++u) {
            const int jj = j + u;
            idx[u] = srcrow[jj < hi ? jj : (hi > lo ? hi - 1 : 0)];
        }
        float4 h[8];
#pragma unroll
        for (int u = 0; u < 8; ++u)
            h[u] = *reinterpret_cast<const float4*>(&Hs[(size_t)idx[u] * 64 + fl]);
#pragma unroll
        for (int u = 0; u < 8; ++u) {
            if (j + u < hi) {
                acc.x += h[u].x; acc.y += h[u].y;
                acc.z += h[u].z; acc.w += h[u].w;
            }
        }
        j += 8;
    }

    if (c < N) {
        const float dc = dinv[c];
        const float4 hs = *reinterpret_cast<const float4*>(&Hs[(size_t)c * 64 + fl]);
        const float4 bl = *reinterpret_cast<const float4*>(&bias[fl]);
        float4 o;
        o.x = dc * (acc.x + hs.x) + bl.x;
        o.y = dc * (acc.y + hs.y) + bl.y;
        o.z = dc * (acc.z + hs.z) + bl.z;
        o.w = dc * (acc.w + hs.w) + bl.w;
        if (RELU) {
            o.x = fmaxf(o.x, 0.f); o.y = fmaxf(o.y, 0.f);
            o.z = fmaxf(o.z, 0.f); o.w = fmaxf(o.w, 0.f);
        }
        *reinterpret_cast<float4*>(&A[(size_t)c * 64 + fl]) = o;
    }
}

// ---------------- mean-pool (batch is sorted) + final linear ----------------

__global__ __launch_bounds__(256)
void pool_kernel(const float* __restrict__ A, const int* __restrict__ batch,
                 float* __restrict__ pooled, int* __restrict__ gcnt, int N) {
    const int g = blockIdx.x >> 3;
    const int stripe = blockIdx.x & 7;
    int lo = 0, hi = N;
    while (lo < hi) { int m = (lo + hi) >> 1; if (batch[m] < g) lo = m + 1; else hi = m; }
    const int beg = lo;
    lo = beg; hi = N;
    while (lo < hi) { int m = (lo + hi) >> 1; if (batch[m] < g + 1) lo = m + 1; else hi = m; }
    const int end = lo;

    const int lane = threadIdx.x & 63;
    const int wsid = stripe * 4 + (threadIdx.x >> 6);
    float acc = 0.f;
    for (int i = beg + wsid; i < end; i += 32)
        acc += A[(size_t)i * 64 + lane];
    atomicAdd(&pooled[g * 64 + lane], acc);
    if (stripe == 0 && threadIdx.x == 0) gcnt[g] = end - beg;
}

__global__ void final_kernel(const float* __restrict__ pooled, const int* __restrict__ gcnt,
                             const float* __restrict__ Wlin, const float* __restrict__ blin,
                             float* __restrict__ out) {
    const int t = threadIdx.x;
    const int g = t >> 1, o = t & 1;
    const float c = (float)max(gcnt[g], 1);
    float acc = 0.f;
    for (int k = 0; k < 64; ++k)
        acc = fmaf(pooled[g * 64 + k], Wlin[k * 2 + o], acc);
    out[g * 2 + o] = acc / c + blin[o];
}

// ---------------- launch ----------------

extern "C" void kernel_launch(void* const* d_in, const int* in_sizes, int n_in,
                              void* d_out, int out_size, void* d_ws, size_t ws_size,
                              hipStream_t stream) {
    const float* x     = (const float*)d_in[0];
    const int*   ei    = (const int*)d_in[1];
    const int*   batch = (const int*)d_in[2];
    const float* W1    = (const float*)d_in[3];
    const float* b1    = (const float*)d_in[4];
    const float* W2    = (const float*)d_in[5];
    const float* b2    = (const float*)d_in[6];
    const float* W3    = (const float*)d_in[7];
    const float* b3    = (const float*)d_in[8];
    const float* Wlin  = (const float*)d_in[9];
    const float* blin  = (const float*)d_in[10];

    const int N = in_sizes[0] / IN_CH;
    const int E = in_sizes[1] / 2;
    const int* row = ei;
    const int* col = ei + E;
    const int nb = (N + 255) >> 8;   // coarse buckets (<=512)

    char* p = (char*)d_ws;
    auto alloc = [&](size_t bytes) {
        char* q = p;
        p += (bytes + 511) & ~(size_t)511;
        return q;
    };
    int*      off    = (int*)alloc((size_t)(N + 1) * 4);
    float*    dinv   = (float*)alloc((size_t)N * 4);
    int*      srcrow = (int*)alloc((size_t)E * 4);
    unsigned* tmp    = (unsigned*)alloc((size_t)E * 4);
    float*    Hbuf   = (float*)alloc((size_t)N * HIDDEN * 4);
    float*    Abuf   = (float*)alloc((size_t)N * HIDDEN * 4);
    int*      bhist  = (int*)alloc(512 * 4);
    int*      bbase  = (int*)alloc(513 * 4);
    int*      bpos   = (int*)alloc(512 * 4);
    float*    pooled = (float*)alloc(64 * 64 * 4);
    int*      gcnt   = (int*)alloc(64 * 4);
    (void)ws_size; (void)n_in; (void)out_size;

    // --- CSR build (bucket sort; also produces dinv for the GEMM epilogue) ---
    hipMemsetAsync(bhist, 0, 512 * 4, stream);
    const int eb = (E + 8191) / 8192;
    bucket_hist_kernel<<<eb, 512, 0, stream>>>(col, bhist, E);
    bucket_scan_kernel<<<1, 512, 0, stream>>>(bhist, bbase, bpos, off, nb, N, E);
    bucket_scatter_kernel<<<eb, 512, 0, stream>>>(row, col, bpos, tmp, E);
    bucket_sort_kernel<<<nb, 256, 0, stream>>>(tmp, bbase, off, dinv, srcrow, N);

    // --- 3 GCN layers ---
    const int gemm_grid   = (N + 63) / 64;
    const int gather_grid = (N + 15) / 16;   // 16 nodes per 256-thread block
    gemm_kernel<IN_CH><<<gemm_grid, 256, 0, stream>>>(x, W1, dinv, Hbuf, N);
    gather_kernel<true><<<gather_grid, 256, 0, stream>>>(Hbuf, dinv, off, srcrow, b1, Abuf, N);
    gemm_kernel<HIDDEN><<<gemm_grid, 256, 0, stream>>>(Abuf, W2, dinv, Hbuf, N);
    gather_kernel<true><<<gather_grid, 256, 0, stream>>>(Hbuf, dinv, off, srcrow, b2, Abuf, N);
    gemm_kernel<HIDDEN><<<gemm_grid, 256, 0, stream>>>(Abuf, W3, dinv, Hbuf, N);
    gather_kernel<false><<<gather_grid, 256, 0, stream>>>(Hbuf, dinv, off, srcrow, b3, Abuf, N);

    // --- mean pool + final linear ---
    hipMemsetAsync(pooled, 0, 64 * 64 * 4, stream);
    pool_kernel<<<512, 256, 0, stream>>>(Abuf, batch, pooled, gcnt, N);
    final_kernel<<<1, 128, 0, stream>>>(pooled, gcnt, Wlin, blin, (float*)d_out);
}

// Round 11
// 335.034 us; speedup vs baseline: 1.2441x; 1.2441x over previous
//
#include <hip/hip_runtime.h>
#include <hip/hip_fp16.h>

#define IN_CH 128
#define HIDDEN 64

// ================= CSR build: two-level LDS-binned counting sort ============
// bucket = col >> 8 (256-node ranges). Packed record (row<<8 | col&255) fits
// 32 bits since row < 2^17 for N=100k. Avoids the 16x write-amplification of
// a direct random 4B scatter (R2 profile: fill_kernel wrote 105MB for 6.4MB).

__global__ __launch_bounds__(512)
void bucket_hist_kernel(const int* __restrict__ col, int* __restrict__ bhist, int E) {
    __shared__ int h[512];
    h[threadIdx.x] = 0;
    __syncthreads();
    const int start = blockIdx.x * 8192;
    const int end = min(start + 8192, E);
    for (int e = start + threadIdx.x; e < end; e += 512)
        atomicAdd(&h[col[e] >> 8], 1);
    __syncthreads();
    if (h[threadIdx.x]) atomicAdd(&bhist[threadIdx.x], h[threadIdx.x]);
}

__global__ __launch_bounds__(512)
void bucket_scan_kernel(const int* __restrict__ bhist, int* __restrict__ bbase,
                        int* __restrict__ bpos, int* __restrict__ off,
                        int nb, int N, int E) {
    __shared__ int s[512];
    const int t = threadIdx.x;
    const int v = (t < nb) ? bhist[t] : 0;
    s[t] = v;
    __syncthreads();
    for (int d = 1; d < 512; d <<= 1) {
        int u = (t >= d) ? s[t - d] : 0;
        __syncthreads();
        s[t] += u;
        __syncthreads();
    }
    const int b = s[t] - v;   // exclusive
    if (t < nb) { bbase[t] = b; bpos[t] = b; }
    if (t == 0) { bbase[nb] = E; off[N] = E; }
}

__global__ __launch_bounds__(512)
void bucket_scatter_kernel(const int* __restrict__ row, const int* __restrict__ col,
                           int* __restrict__ bpos, unsigned* __restrict__ tmp, int E) {
    __shared__ int h[512];
    __shared__ int base[512];
    h[threadIdx.x] = 0;
    __syncthreads();
    const int start = blockIdx.x * 8192;
    const int end = min(start + 8192, E);
    for (int e = start + threadIdx.x; e < end; e += 512)
        atomicAdd(&h[col[e] >> 8], 1);
    __syncthreads();
    const int i = threadIdx.x;
    base[i] = h[i] ? atomicAdd(&bpos[i], h[i]) : 0;
    h[i] = 0;
    __syncthreads();
    for (int e = start + threadIdx.x; e < end; e += 512) {
        const int c = col[e];
        const int bk = c >> 8;
        const int p = base[bk] + atomicAdd(&h[bk], 1);
        tmp[p] = ((unsigned)row[e] << 8) | (unsigned)(c & 255);
    }
}

__global__ __launch_bounds__(256)
void bucket_sort_kernel(const unsigned* __restrict__ tmp, const int* __restrict__ bbase,
                        int* __restrict__ off, float* __restrict__ dinv,
                        int* __restrict__ srcrow, int N) {
    __shared__ int cnt[256];
    __shared__ int sc[256];
    const int b = blockIdx.x;
    const int node0 = b << 8;
    const int t = threadIdx.x;
    const int lo = bbase[b], hi = bbase[b + 1];
    cnt[t] = 0;
    __syncthreads();
    for (int j = lo + t; j < hi; j += 256)
        atomicAdd(&cnt[tmp[j] & 255u], 1);
    __syncthreads();
    const int v = cnt[t];
    sc[t] = v;
    __syncthreads();
    for (int d = 1; d < 256; d <<= 1) {
        int u = (t >= d) ? sc[t - d] : 0;
        __syncthreads();
        sc[t] += u;
        __syncthreads();
    }
    const int excl = sc[t] - v;
    const int node = node0 + t;
    if (node < N) {
        off[node] = lo + excl;
        dinv[node] = rsqrtf((float)v + 1.0f);   // deg = 1 (self-loop) + in-degree
    }
    cnt[t] = lo + excl;   // reuse as running write cursor
    __syncthreads();
    for (int j = lo + t; j < hi; j += 256) {
        const unsigned pk = tmp[j];
        const int p = atomicAdd(&cnt[pk & 255u], 1);
        srcrow[p] = (int)(pk >> 8);
    }
}

// ---------------- tiled fp32 GEMM: Hs[N,64] = fp16((X[N,K] @ W[K,64])*dinv) --
// Hs stored as fp16 (128B rows): R10 showed the gather is bytes-bound on the
// per-XCD-L2 compulsory re-fetch of Hs (8 x 25.6MB ~ 190MB at ~3.2TB/s L3).
// Halving the row halves that term. Accumulation & everything else fp32.

template <int K>
__global__ __launch_bounds__(256)
void gemm_kernel(const float* __restrict__ X, const float* __restrict__ W,
                 const float* __restrict__ dinv, __half* __restrict__ Hs, int N) {
    constexpr int BK = 16;
    __shared__ float xs[BK][64];
    __shared__ float ws[BK][64];
    const int tid  = threadIdx.x;
    const int row0 = blockIdx.x * 64;
    const int tx4  = (tid & 15) << 2;
    const int ty4  = (tid >> 4) << 2;
    const int lrow = tid >> 2;
    const int kq   = (tid & 3) << 2;
    const int wk   = tid >> 4;
    const int wc   = (tid & 15) << 2;
    int grow = row0 + lrow;
    if (grow >= N) grow = N - 1;

    float acc[4][4] = {};
    for (int k0 = 0; k0 < K; k0 += BK) {
        const float4 xv = *reinterpret_cast<const float4*>(&X[(size_t)grow * K + k0 + kq]);
        const float4 wv = *reinterpret_cast<const float4*>(&W[(size_t)(k0 + wk) * 64 + wc]);
        __syncthreads();
        xs[kq + 0][lrow] = xv.x;
        xs[kq + 1][lrow] = xv.y;
        xs[kq + 2][lrow] = xv.z;
        xs[kq + 3][lrow] = xv.w;
        *reinterpret_cast<float4*>(&ws[wk][wc]) = wv;
        __syncthreads();
#pragma unroll
        for (int k = 0; k < BK; ++k) {
            const float4 a = *reinterpret_cast<const float4*>(&xs[k][ty4]);
            const float4 b = *reinterpret_cast<const float4*>(&ws[k][tx4]);
            const float av[4] = {a.x, a.y, a.z, a.w};
            const float bv[4] = {b.x, b.y, b.z, b.w};
#pragma unroll
            for (int r = 0; r < 4; ++r)
#pragma unroll
                for (int c = 0; c < 4; ++c)
                    acc[r][c] = fmaf(av[r], bv[c], acc[r][c]);
        }
    }
#pragma unroll
    for (int r = 0; r < 4; ++r) {
        int n = row0 + ty4 + r;
        if (n < N) {
            const float dn = dinv[n];
            union { uint2 u; __half2 h2[2]; } pk;
            pk.h2[0] = __floats2half2_rn(acc[r][0] * dn, acc[r][1] * dn);
            pk.h2[1] = __floats2half2_rn(acc[r][2] * dn, acc[r][3] * dn);
            *reinterpret_cast<uint2*>(&Hs[(size_t)n * 64 + tx4]) = pk.u;
        }
    }
}

// ---------------- pull-style aggregation, fused self-term + bias (+ReLU) ----
// 4 nodes per wave: quarter-wave (16 lanes) per node, 4 fp16 feats/lane (8B).
// One gather instruction fetches four 128B rows. fp32 accumulate; A stays fp32.

template <bool RELU>
__global__ __launch_bounds__(256)
void gather_kernel(const __half* __restrict__ Hs, const float* __restrict__ dinv,
                   const int* __restrict__ off, const int* __restrict__ srcrow,
                   const float* __restrict__ bias, float* __restrict__ A, int N) {
    const int tid  = threadIdx.x;
    const int lane = tid & 63;
    const int q    = lane >> 4;              // quarter 0..3 = node sub-id
    const int fl   = (lane & 15) << 2;       // feature base (0,4,...,60)
    const int wid  = tid >> 6;               // wave 0..3
    const int c    = blockIdx.x * 16 + wid * 4 + q;
    const int cc   = (c < N) ? c : N - 1;    // clamp; store is guarded
    const int lo = off[cc], hi = off[cc + 1];

    float4 acc = make_float4(0.f, 0.f, 0.f, 0.f);
    int j = lo;
    while (__any(j < hi)) {
        int idx[8];
#pragma unroll
        for (int u = 0; u < 8; ++u) {
            const int jj = j + u;
            idx[u] = srcrow[jj < hi ? jj : (hi > lo ? hi - 1 : 0)];
        }
        uint2 hv[8];
#pragma unroll
        for (int u = 0; u < 8; ++u)
            hv[u] = *reinterpret_cast<const uint2*>(&Hs[(size_t)idx[u] * 64 + fl]);
#pragma unroll
        for (int u = 0; u < 8; ++u) {
            if (j + u < hi) {
                union { uint2 uu; __half2 h2[2]; } v; v.uu = hv[u];
                const float2 a = __half22float2(v.h2[0]);
                const float2 b = __half22float2(v.h2[1]);
                acc.x += a.x; acc.y += a.y; acc.z += b.x; acc.w += b.y;
            }
        }
        j += 8;
    }

    if (c < N) {
        const float dc = dinv[c];
        union { uint2 uu; __half2 h2[2]; } sv;
        sv.uu = *reinterpret_cast<const uint2*>(&Hs[(size_t)c * 64 + fl]);
        const float2 s0 = __half22float2(sv.h2[0]);
        const float2 s1 = __half22float2(sv.h2[1]);
        const float4 bl = *reinterpret_cast<const float4*>(&bias[fl]);
        float4 o;
        o.x = dc * (acc.x + s0.x) + bl.x;
        o.y = dc * (acc.y + s0.y) + bl.y;
        o.z = dc * (acc.z + s1.x) + bl.z;
        o.w = dc * (acc.w + s1.y) + bl.w;
        if (RELU) {
            o.x = fmaxf(o.x, 0.f); o.y = fmaxf(o.y, 0.f);
            o.z = fmaxf(o.z, 0.f); o.w = fmaxf(o.w, 0.f);
        }
        *reinterpret_cast<float4*>(&A[(size_t)c * 64 + fl]) = o;
    }
}

// ---------------- mean-pool (batch is sorted) + final linear ----------------

__global__ __launch_bounds__(256)
void pool_kernel(const float* __restrict__ A, const int* __restrict__ batch,
                 float* __restrict__ pooled, int* __restrict__ gcnt, int N) {
    const int g = blockIdx.x >> 3;
    const int stripe = blockIdx.x & 7;
    int lo = 0, hi = N;
    while (lo < hi) { int m = (lo + hi) >> 1; if (batch[m] < g) lo = m + 1; else hi = m; }
    const int beg = lo;
    lo = beg; hi = N;
    while (lo < hi) { int m = (lo + hi) >> 1; if (batch[m] < g + 1) lo = m + 1; else hi = m; }
    const int end = lo;

    const int lane = threadIdx.x & 63;
    const int wsid = stripe * 4 + (threadIdx.x >> 6);
    float acc = 0.f;
    for (int i = beg + wsid; i < end; i += 32)
        acc += A[(size_t)i * 64 + lane];
    atomicAdd(&pooled[g * 64 + lane], acc);
    if (stripe == 0 && threadIdx.x == 0) gcnt[g] = end - beg;
}

__global__ void final_kernel(const float* __restrict__ pooled, const int* __restrict__ gcnt,
                             const float* __restrict__ Wlin, const float* __restrict__ blin,
                             float* __restrict__ out) {
    const int t = threadIdx.x;
    const int g = t >> 1, o = t & 1;
    const float c = (float)max(gcnt[g], 1);
    float acc = 0.f;
    for (int k = 0; k < 64; ++k)
        acc = fmaf(pooled[g * 64 + k], Wlin[k * 2 + o], acc);
    out[g * 2 + o] = acc / c + blin[o];
}

// ---------------- launch ----------------

extern "C" void kernel_launch(void* const* d_in, const int* in_sizes, int n_in,
                              void* d_out, int out_size, void* d_ws, size_t ws_size,
                              hipStream_t stream) {
    const float* x     = (const float*)d_in[0];
    const int*   ei    = (const int*)d_in[1];
    const int*   batch = (const int*)d_in[2];
    const float* W1    = (const float*)d_in[3];
    const float* b1    = (const float*)d_in[4];
    const float* W2    = (const float*)d_in[5];
    const float* b2    = (const float*)d_in[6];
    const float* W3    = (const float*)d_in[7];
    const float* b3    = (const float*)d_in[8];
    const float* Wlin  = (const float*)d_in[9];
    const float* blin  = (const float*)d_in[10];

    const int N = in_sizes[0] / IN_CH;
    const int E = in_sizes[1] / 2;
    const int* row = ei;
    const int* col = ei + E;
    const int nb = (N + 255) >> 8;   // coarse buckets (<=512)

    char* p = (char*)d_ws;
    auto alloc = [&](size_t bytes) {
        char* q = p;
        p += (bytes + 511) & ~(size_t)511;
        return q;
    };
    int*      off    = (int*)alloc((size_t)(N + 1) * 4);
    float*    dinv   = (float*)alloc((size_t)N * 4);
    int*      srcrow = (int*)alloc((size_t)E * 4);
    unsigned* tmp    = (unsigned*)alloc((size_t)E * 4);
    __half*   Hbuf   = (__half*)alloc((size_t)N * HIDDEN * 2);
    float*    Abuf   = (float*)alloc((size_t)N * HIDDEN * 4);
    int*      bhist  = (int*)alloc(512 * 4);
    int*      bbase  = (int*)alloc(513 * 4);
    int*      bpos   = (int*)alloc(512 * 4);
    float*    pooled = (float*)alloc(64 * 64 * 4);
    int*      gcnt   = (int*)alloc(64 * 4);
    (void)ws_size; (void)n_in; (void)out_size;

    // --- CSR build (bucket sort; also produces dinv for the GEMM epilogue) ---
    hipMemsetAsync(bhist, 0, 512 * 4, stream);
    const int eb = (E + 8191) / 8192;
    bucket_hist_kernel<<<eb, 512, 0, stream>>>(col, bhist, E);
    bucket_scan_kernel<<<1, 512, 0, stream>>>(bhist, bbase, bpos, off, nb, N, E);
    bucket_scatter_kernel<<<eb, 512, 0, stream>>>(row, col, bpos, tmp, E);
    bucket_sort_kernel<<<nb, 256, 0, stream>>>(tmp, bbase, off, dinv, srcrow, N);

    // --- 3 GCN layers ---
    const int gemm_grid   = (N + 63) / 64;
    const int gather_grid = (N + 15) / 16;   // 16 nodes per 256-thread block
    gemm_kernel<IN_CH><<<gemm_grid, 256, 0, stream>>>(x, W1, dinv, Hbuf, N);
    gather_kernel<true><<<gather_grid, 256, 0, stream>>>(Hbuf, dinv, off, srcrow, b1, Abuf, N);
    gemm_kernel<HIDDEN><<<gemm_grid, 256, 0, stream>>>(Abuf, W2, dinv, Hbuf, N);
    gather_kernel<true><<<gather_grid, 256, 0, stream>>>(Hbuf, dinv, off, srcrow, b2, Abuf, N);
    gemm_kernel<HIDDEN><<<gemm_grid, 256, 0, stream>>>(Abuf, W3, dinv, Hbuf, N);
    gather_kernel<false><<<gather_grid, 256, 0, stream>>>(Hbuf, dinv, off, srcrow, b3, Abuf, N);

    // --- mean pool + final linear ---
    hipMemsetAsync(pooled, 0, 64 * 64 * 4, stream);
    pool_kernel<<<512, 256, 0, stream>>>(Abuf, batch, pooled, gcnt, N);
    final_kernel<<<1, 128, 0, stream>>>(pooled, gcnt, Wlin, blin, (float*)d_out);
}

// Round 12
// 313.963 us; speedup vs baseline: 1.3276x; 1.0671x over previous
//
#include <hip/hip_runtime.h>
#include <hip/hip_fp16.h>

#define IN_CH 128
#define HIDDEN 64

typedef _Float16 half8 __attribute__((ext_vector_type(8)));
typedef float f32x4 __attribute__((ext_vector_type(4)));

// ================= CSR build: two-level LDS-binned counting sort ============

__global__ __launch_bounds__(512)
void bucket_hist_kernel(const int* __restrict__ col, int* __restrict__ bhist, int E) {
    __shared__ int h[512];
    h[threadIdx.x] = 0;
    __syncthreads();
    const int start = blockIdx.x * 8192;
    const int end = min(start + 8192, E);
    for (int e = start + threadIdx.x; e < end; e += 512)
        atomicAdd(&h[col[e] >> 8], 1);
    __syncthreads();
    if (h[threadIdx.x]) atomicAdd(&bhist[threadIdx.x], h[threadIdx.x]);
}

__global__ __launch_bounds__(512)
void bucket_scan_kernel(const int* __restrict__ bhist, int* __restrict__ bbase,
                        int* __restrict__ bpos, int* __restrict__ off,
                        int nb, int N, int E) {
    __shared__ int s[512];
    const int t = threadIdx.x;
    const int v = (t < nb) ? bhist[t] : 0;
    s[t] = v;
    __syncthreads();
    for (int d = 1; d < 512; d <<= 1) {
        int u = (t >= d) ? s[t - d] : 0;
        __syncthreads();
        s[t] += u;
        __syncthreads();
    }
    const int b = s[t] - v;   // exclusive
    if (t < nb) { bbase[t] = b; bpos[t] = b; }
    if (t == 0) { bbase[nb] = E; off[N] = E; }
}

__global__ __launch_bounds__(512)
void bucket_scatter_kernel(const int* __restrict__ row, const int* __restrict__ col,
                           int* __restrict__ bpos, unsigned* __restrict__ tmp, int E) {
    __shared__ int h[512];
    __shared__ int base[512];
    h[threadIdx.x] = 0;
    __syncthreads();
    const int start = blockIdx.x * 8192;
    const int end = min(start + 8192, E);
    for (int e = start + threadIdx.x; e < end; e += 512)
        atomicAdd(&h[col[e] >> 8], 1);
    __syncthreads();
    const int i = threadIdx.x;
    base[i] = h[i] ? atomicAdd(&bpos[i], h[i]) : 0;
    h[i] = 0;
    __syncthreads();
    for (int e = start + threadIdx.x; e < end; e += 512) {
        const int c = col[e];
        const int bk = c >> 8;
        const int p = base[bk] + atomicAdd(&h[bk], 1);
        tmp[p] = ((unsigned)row[e] << 8) | (unsigned)(c & 255);
    }
}

__global__ __launch_bounds__(256)
void bucket_sort_kernel(const unsigned* __restrict__ tmp, const int* __restrict__ bbase,
                        int* __restrict__ off, float* __restrict__ dinv,
                        int* __restrict__ srcrow, int N) {
    __shared__ int cnt[256];
    __shared__ int sc[256];
    const int b = blockIdx.x;
    const int node0 = b << 8;
    const int t = threadIdx.x;
    const int lo = bbase[b], hi = bbase[b + 1];
    cnt[t] = 0;
    __syncthreads();
    for (int j = lo + t; j < hi; j += 256)
        atomicAdd(&cnt[tmp[j] & 255u], 1);
    __syncthreads();
    const int v = cnt[t];
    sc[t] = v;
    __syncthreads();
    for (int d = 1; d < 256; d <<= 1) {
        int u = (t >= d) ? sc[t - d] : 0;
        __syncthreads();
        sc[t] += u;
        __syncthreads();
    }
    const int excl = sc[t] - v;
    const int node = node0 + t;
    if (node < N) {
        off[node] = lo + excl;
        dinv[node] = rsqrtf((float)v + 1.0f);   // deg = 1 (self-loop) + in-degree
    }
    cnt[t] = lo + excl;   // reuse as running write cursor
    __syncthreads();
    for (int j = lo + t; j < hi; j += 256) {
        const unsigned pk = tmp[j];
        const int p = atomicAdd(&cnt[pk & 255u], 1);
        srcrow[p] = (int)(pk >> 8);
    }
}

// ============ W repack to MFMA B-fragment order (one block, per layer) ======
// Wp[((s*4+g)*64 + lane)*8 + j] = fp16(W[32s + 8*(lane>>4) + j][16g + (lane&15)])

__global__ void pack_kernel(const float* __restrict__ W, _Float16* __restrict__ Wp, int K) {
    const int tid = threadIdx.x;          // 256 = 4 groups x 64 lanes
    const int l = tid & 63;
    const int g = tid >> 6;
    const int kb = (l >> 4) * 8;
    const int c = 16 * g + (l & 15);
    for (int s = 0; s < K / 32; ++s) {
        half8 v;
#pragma unroll
        for (int j = 0; j < 8; ++j)
            v[j] = (_Float16)W[(size_t)(32 * s + kb + j) * 64 + c];
        *reinterpret_cast<half8*>(&Wp[((size_t)(s * 4 + g) * 64 + l) * 8]) = v;
    }
}

// ============ MFMA fp16 GEMM: Hs[N,64] = fp16((A[N,K]@W[K,64])*dinv) ========
// 64 rows/block, 4 waves (wave w -> rows 16w..16w+15), K-step 32, no LDS.
// mfma_f32_16x16x32_f16: A lane-map row=l&15,k=8*(l>>4)+j; B col=l&15 (packed);
// C/D col=l&15, row=(l>>4)*4+reg (m89-verified layout).

template <int K, bool AF32>
__global__ __launch_bounds__(256)
void gemm_mfma_kernel(const void* __restrict__ Aptr, const _Float16* __restrict__ Wp,
                      const float* __restrict__ dinv, _Float16* __restrict__ Hs, int N) {
    const int tid = threadIdx.x;
    const int l = tid & 63;
    const int w = tid >> 6;
    const int r0 = blockIdx.x * 64 + w * 16;
    const int arow_ = r0 + (l & 15);
    const int arow = arow_ < N ? arow_ : N - 1;   // clamp; stores guarded
    const int kb = (l >> 4) * 8;

    f32x4 acc[4] = {};
#pragma unroll
    for (int s = 0; s < K / 32; ++s) {
        half8 a;
        if constexpr (AF32) {
            const float* A = (const float*)Aptr;
            const float4 f0 = *reinterpret_cast<const float4*>(&A[(size_t)arow * K + 32 * s + kb]);
            const float4 f1 = *reinterpret_cast<const float4*>(&A[(size_t)arow * K + 32 * s + kb + 4]);
            a[0] = (_Float16)f0.x; a[1] = (_Float16)f0.y;
            a[2] = (_Float16)f0.z; a[3] = (_Float16)f0.w;
            a[4] = (_Float16)f1.x; a[5] = (_Float16)f1.y;
            a[6] = (_Float16)f1.z; a[7] = (_Float16)f1.w;
        } else {
            const _Float16* A = (const _Float16*)Aptr;
            a = *reinterpret_cast<const half8*>(&A[(size_t)arow * K + 32 * s + kb]);
        }
        const half8* Wb = reinterpret_cast<const half8*>(&Wp[(size_t)(s * 4) * 64 * 8]);
#pragma unroll
        for (int g = 0; g < 4; ++g) {
            const half8 b = Wb[g * 64 + l];
            acc[g] = __builtin_amdgcn_mfma_f32_16x16x32_f16(a, b, acc[g], 0, 0, 0);
        }
    }

    const int rb = r0 + (l >> 4) * 4;
    float dv[4];
#pragma unroll
    for (int j = 0; j < 4; ++j) {
        const int r = rb + j;
        dv[j] = dinv[r < N ? r : N - 1];
    }
#pragma unroll
    for (int g = 0; g < 4; ++g) {
#pragma unroll
        for (int j = 0; j < 4; ++j) {
            const int r = rb + j;
            if (r < N)
                Hs[(size_t)r * 64 + g * 16 + (l & 15)] = (_Float16)(acc[g][j] * dv[j]);
        }
    }
}

// ---------------- pull-style aggregation, fused self-term + bias (+ReLU) ----
// 4 nodes per wave: quarter-wave (16 lanes) per node, 4 fp16 feats/lane (8B).
// fp32 accumulate; A output now fp16 (halves gather writes + gemm2/3 reads).

template <bool RELU>
__global__ __launch_bounds__(256)
void gather_kernel(const __half* __restrict__ Hs, const float* __restrict__ dinv,
                   const int* __restrict__ off, const int* __restrict__ srcrow,
                   const float* __restrict__ bias, __half* __restrict__ A, int N) {
    const int tid  = threadIdx.x;
    const int lane = tid & 63;
    const int q    = lane >> 4;              // quarter 0..3 = node sub-id
    const int fl   = (lane & 15) << 2;       // feature base (0,4,...,60)
    const int wid  = tid >> 6;               // wave 0..3
    const int c    = blockIdx.x * 16 + wid * 4 + q;
    const int cc   = (c < N) ? c : N - 1;    // clamp; store is guarded
    const int lo = off[cc], hi = off[cc + 1];

    float4 acc = make_float4(0.f, 0.f, 0.f, 0.f);
    int j = lo;
    while (__any(j < hi)) {
        int idx[8];
#pragma unroll
        for (int u = 0; u < 8; ++u) {
            const int jj = j + u;
            idx[u] = srcrow[jj < hi ? jj : (hi > lo ? hi - 1 : 0)];
        }
        uint2 hv[8];
#pragma unroll
        for (int u = 0; u < 8; ++u)
            hv[u] = *reinterpret_cast<const uint2*>(&Hs[(size_t)idx[u] * 64 + fl]);
#pragma unroll
        for (int u = 0; u < 8; ++u) {
            if (j + u < hi) {
                union { uint2 uu; __half2 h2[2]; } v; v.uu = hv[u];
                const float2 a = __half22float2(v.h2[0]);
                const float2 b = __half22float2(v.h2[1]);
                acc.x += a.x; acc.y += a.y; acc.z += b.x; acc.w += b.y;
            }
        }
        j += 8;
    }

    if (c < N) {
        const float dc = dinv[c];
        union { uint2 uu; __half2 h2[2]; } sv;
        sv.uu = *reinterpret_cast<const uint2*>(&Hs[(size_t)c * 64 + fl]);
        const float2 s0 = __half22float2(sv.h2[0]);
        const float2 s1 = __half22float2(sv.h2[1]);
        const float4 bl = *reinterpret_cast<const float4*>(&bias[fl]);
        float4 o;
        o.x = dc * (acc.x + s0.x) + bl.x;
        o.y = dc * (acc.y + s0.y) + bl.y;
        o.z = dc * (acc.z + s1.x) + bl.z;
        o.w = dc * (acc.w + s1.y) + bl.w;
        if (RELU) {
            o.x = fmaxf(o.x, 0.f); o.y = fmaxf(o.y, 0.f);
            o.z = fmaxf(o.z, 0.f); o.w = fmaxf(o.w, 0.f);
        }
        union { uint2 uu; __half2 h2[2]; } ov;
        ov.h2[0] = __floats2half2_rn(o.x, o.y);
        ov.h2[1] = __floats2half2_rn(o.z, o.w);
        *reinterpret_cast<uint2*>(&A[(size_t)c * 64 + fl]) = ov.uu;
    }
}

// ---------------- mean-pool (batch is sorted) + final linear ----------------

__global__ __launch_bounds__(256)
void pool_kernel(const __half* __restrict__ A, const int* __restrict__ batch,
                 float* __restrict__ pooled, int* __restrict__ gcnt, int N) {
    const int g = blockIdx.x >> 3;
    const int stripe = blockIdx.x & 7;
    int lo = 0, hi = N;
    while (lo < hi) { int m = (lo + hi) >> 1; if (batch[m] < g) lo = m + 1; else hi = m; }
    const int beg = lo;
    lo = beg; hi = N;
    while (lo < hi) { int m = (lo + hi) >> 1; if (batch[m] < g + 1) lo = m + 1; else hi = m; }
    const int end = lo;

    const int lane = threadIdx.x & 63;
    const int wsid = stripe * 4 + (threadIdx.x >> 6);
    float acc = 0.f;
    for (int i = beg + wsid; i < end; i += 32)
        acc += __half2float(A[(size_t)i * 64 + lane]);
    atomicAdd(&pooled[g * 64 + lane], acc);
    if (stripe == 0 && threadIdx.x == 0) gcnt[g] = end - beg;
}

__global__ void final_kernel(const float* __restrict__ pooled, const int* __restrict__ gcnt,
                             const float* __restrict__ Wlin, const float* __restrict__ blin,
                             float* __restrict__ out) {
    const int t = threadIdx.x;
    const int g = t >> 1, o = t & 1;
    const float c = (float)max(gcnt[g], 1);
    float acc = 0.f;
    for (int k = 0; k < 64; ++k)
        acc = fmaf(pooled[g * 64 + k], Wlin[k * 2 + o], acc);
    out[g * 2 + o] = acc / c + blin[o];
}

// ---------------- launch ----------------

extern "C" void kernel_launch(void* const* d_in, const int* in_sizes, int n_in,
                              void* d_out, int out_size, void* d_ws, size_t ws_size,
                              hipStream_t stream) {
    const float* x     = (const float*)d_in[0];
    const int*   ei    = (const int*)d_in[1];
    const int*   batch = (const int*)d_in[2];
    const float* W1    = (const float*)d_in[3];
    const float* b1    = (const float*)d_in[4];
    const float* W2    = (const float*)d_in[5];
    const float* b2    = (const float*)d_in[6];
    const float* W3    = (const float*)d_in[7];
    const float* b3    = (const float*)d_in[8];
    const float* Wlin  = (const float*)d_in[9];
    const float* blin  = (const float*)d_in[10];

    const int N = in_sizes[0] / IN_CH;
    const int E = in_sizes[1] / 2;
    const int* row = ei;
    const int* col = ei + E;
    const int nb = (N + 255) >> 8;   // coarse buckets (<=512)

    char* p = (char*)d_ws;
    auto alloc = [&](size_t bytes) {
        char* q = p;
        p += (bytes + 511) & ~(size_t)511;
        return q;
    };
    int*      off    = (int*)alloc((size_t)(N + 1) * 4);
    float*    dinv   = (float*)alloc((size_t)N * 4);
    int*      srcrow = (int*)alloc((size_t)E * 4);
    unsigned* tmp    = (unsigned*)alloc((size_t)E * 4);
    _Float16* Hbuf   = (_Float16*)alloc((size_t)N * HIDDEN * 2);
    _Float16* Abuf   = (_Float16*)alloc((size_t)N * HIDDEN * 2);
    _Float16* Wp1    = (_Float16*)alloc((size_t)IN_CH * 64 * 2);
    _Float16* Wp2    = (_Float16*)alloc((size_t)HIDDEN * 64 * 2);
    _Float16* Wp3    = (_Float16*)alloc((size_t)HIDDEN * 64 * 2);
    int*      bhist  = (int*)alloc(512 * 4);
    int*      bbase  = (int*)alloc(513 * 4);
    int*      bpos   = (int*)alloc(512 * 4);
    float*    pooled = (float*)alloc(64 * 64 * 4);
    int*      gcnt   = (int*)alloc(64 * 4);
    (void)ws_size; (void)n_in; (void)out_size;

    // --- CSR build (bucket sort; also produces dinv for the GEMM epilogue) ---
    hipMemsetAsync(bhist, 0, 512 * 4, stream);
    const int eb = (E + 8191) / 8192;
    bucket_hist_kernel<<<eb, 512, 0, stream>>>(col, bhist, E);
    bucket_scan_kernel<<<1, 512, 0, stream>>>(bhist, bbase, bpos, off, nb, N, E);
    bucket_scatter_kernel<<<eb, 512, 0, stream>>>(row, col, bpos, tmp, E);
    bucket_sort_kernel<<<nb, 256, 0, stream>>>(tmp, bbase, off, dinv, srcrow, N);

    // --- W fragment repack (tiny) ---
    pack_kernel<<<1, 256, 0, stream>>>(W1, Wp1, IN_CH);
    pack_kernel<<<1, 256, 0, stream>>>(W2, Wp2, HIDDEN);
    pack_kernel<<<1, 256, 0, stream>>>(W3, Wp3, HIDDEN);

    // --- 3 GCN layers ---
    const int gemm_grid   = (N + 63) / 64;
    const int gather_grid = (N + 15) / 16;   // 16 nodes per 256-thread block
    gemm_mfma_kernel<IN_CH, true><<<gemm_grid, 256, 0, stream>>>(x, Wp1, dinv, Hbuf, N);
    gather_kernel<true><<<gather_grid, 256, 0, stream>>>((const __half*)Hbuf, dinv, off, srcrow, b1, (__half*)Abuf, N);
    gemm_mfma_kernel<HIDDEN, false><<<gemm_grid, 256, 0, stream>>>(Abuf, Wp2, dinv, Hbuf, N);
    gather_kernel<true><<<gather_grid, 256, 0, stream>>>((const __half*)Hbuf, dinv, off, srcrow, b2, (__half*)Abuf, N);
    gemm_mfma_kernel<HIDDEN, false><<<gemm_grid, 256, 0, stream>>>(Abuf, Wp3, dinv, Hbuf, N);
    gather_kernel<false><<<gather_grid, 256, 0, stream>>>((const __half*)Hbuf, dinv, off, srcrow, b3, (__half*)Abuf, N);

    // --- mean pool + final linear ---
    hipMemsetAsync(pooled, 0, 64 * 64 * 4, stream);
    pool_kernel<<<512, 256, 0, stream>>>((const __half*)Abuf, batch, pooled, gcnt, N);
    final_kernel<<<1, 128, 0, stream>>>(pooled, gcnt, Wlin, blin, (float*)d_out);
}

// Round 16
// 302.663 us; speedup vs baseline: 1.3771x; 1.0373x over previous
//
#include <hip/hip_runtime.h>
#include <hip/hip_fp16.h>

#define IN_CH 128
#define HIDDEN 64
#define NB 1024            // max coarse buckets (128 nodes each)

typedef _Float16 half8 __attribute__((ext_vector_type(8)));
typedef float f32x4 __attribute__((ext_vector_type(4)));

// ============ W repack to MFMA B-fragment order + bhist zeroing =============
// One launch, 3 blocks (one per layer). Block 0 also zeroes bhist.

__global__ __launch_bounds__(256)
void pack3_kernel(const float* __restrict__ W1, const float* __restrict__ W2,
                  const float* __restrict__ W3, _Float16* __restrict__ Wp1,
                  _Float16* __restrict__ Wp2, _Float16* __restrict__ Wp3,
                  int* __restrict__ bhist) {
    const int tid = threadIdx.x;
    if (blockIdx.x == 0)
        for (int i = tid; i < NB; i += 256) bhist[i] = 0;
    const float* W = (blockIdx.x == 0) ? W1 : (blockIdx.x == 1) ? W2 : W3;
    _Float16* Wp   = (blockIdx.x == 0) ? Wp1 : (blockIdx.x == 1) ? Wp2 : Wp3;
    const int K    = (blockIdx.x == 0) ? IN_CH : HIDDEN;
    const int l = tid & 63;
    const int g = tid >> 6;
    const int kb = (l >> 4) * 8;
    const int c = 16 * g + (l & 15);
    for (int s = 0; s < K / 32; ++s) {
        half8 v;
#pragma unroll
        for (int j = 0; j < 8; ++j)
            v[j] = (_Float16)W[(size_t)(32 * s + kb + j) * 64 + c];
        *reinterpret_cast<half8*>(&Wp[((size_t)(s * 4 + g) * 64 + l) * 8]) = v;
    }
}

// ================= CSR build: two-level LDS-binned counting sort ============
// bucket = col >> 7 (128-node ranges, 782 buckets -> 3 blocks/CU in sort).
// Packed record (row<<7 | col&127) fits 24 bits (row < 2^17).

__global__ __launch_bounds__(1024)
void bucket_hist_kernel(const int* __restrict__ col, int* __restrict__ bhist, int E) {
    __shared__ int h[NB];
    h[threadIdx.x] = 0;
    __syncthreads();
    const int start = blockIdx.x * 8192;
    const int end = min(start + 8192, E);
    for (int e = start + threadIdx.x; e < end; e += 1024)
        atomicAdd(&h[col[e] >> 7], 1);
    __syncthreads();
    if (h[threadIdx.x]) atomicAdd(&bhist[threadIdx.x], h[threadIdx.x]);
}

// also zeroes `pooled` (64x64 floats) for the late pool phase
__global__ __launch_bounds__(1024)
void bucket_scan_kernel(const int* __restrict__ bhist, int* __restrict__ bbase,
                        int* __restrict__ bpos, int* __restrict__ off,
                        float* __restrict__ pooled, int N, int E) {
    __shared__ int s[NB];
    const int t = threadIdx.x;
    pooled[t] = 0.f; pooled[t + 1024] = 0.f;
    pooled[t + 2048] = 0.f; pooled[t + 3072] = 0.f;
    const int v = bhist[t];          // bins >= nb are zero
    s[t] = v;
    __syncthreads();
    for (int d = 1; d < 1024; d <<= 1) {
        int u = (t >= d) ? s[t - d] : 0;
        __syncthreads();
        s[t] += u;
        __syncthreads();
    }
    const int b = s[t] - v;          // exclusive
    bbase[t] = b;
    bpos[t] = b;
    if (t == 0) { bbase[NB] = E; off[N] = E; }
}

__global__ __launch_bounds__(1024)
void bucket_scatter_kernel(const int* __restrict__ row, const int* __restrict__ col,
                           int* __restrict__ bpos, unsigned* __restrict__ tmp, int E) {
    __shared__ int h[NB];
    __shared__ int base[NB];
    h[threadIdx.x] = 0;
    __syncthreads();
    const int start = blockIdx.x * 8192;
    const int end = min(start + 8192, E);
    for (int e = start + threadIdx.x; e < end; e += 1024)
        atomicAdd(&h[col[e] >> 7], 1);
    __syncthreads();
    const int i = threadIdx.x;
    base[i] = h[i] ? atomicAdd(&bpos[i], h[i]) : 0;
    h[i] = 0;
    __syncthreads();
    for (int e = start + threadIdx.x; e < end; e += 1024) {
        const int c = col[e];
        const int bk = c >> 7;
        const int p = base[bk] + atomicAdd(&h[bk], 1);
        tmp[p] = ((unsigned)row[e] << 7) | (unsigned)(c & 127);
    }
}

__global__ __launch_bounds__(256)
void bucket_sort_kernel(const unsigned* __restrict__ tmp, const int* __restrict__ bbase,
                        int* __restrict__ off, float* __restrict__ dinv,
                        int* __restrict__ srcrow, int N) {
    __shared__ int cnt[128];
    __shared__ int sc[128];
    const int b = blockIdx.x;
    const int node0 = b << 7;
    const int t = threadIdx.x;
    const int lo = bbase[b], hi = bbase[b + 1];
    if (t < 128) cnt[t] = 0;
    __syncthreads();
    for (int j = lo + t; j < hi; j += 256)
        atomicAdd(&cnt[tmp[j] & 127u], 1);
    __syncthreads();
    const int v = (t < 128) ? cnt[t] : 0;
    if (t < 128) sc[t] = v;
    __syncthreads();
    for (int d = 1; d < 128; d <<= 1) {
        int u = (t >= d && t < 128) ? sc[t - d] : 0;
        __syncthreads();
        if (t < 128) sc[t] += u;
        __syncthreads();
    }
    if (t < 128) {
        const int excl = sc[t] - v;
        const int node = node0 + t;
        if (node < N) {
            off[node] = lo + excl;
            dinv[node] = rsqrtf((float)v + 1.0f);  // deg = 1 (self-loop) + in-deg
        }
        cnt[t] = lo + excl;   // running write cursor
    }
    __syncthreads();
    for (int j = lo + t; j < hi; j += 256) {
        const unsigned pk = tmp[j];
        const int p = atomicAdd(&cnt[pk & 127u], 1);
        srcrow[p] = (int)(pk >> 7);
    }
}

// ============ MFMA fp16 GEMM: Hs[N,64] = fp16((A[N,K]@W[K,64])*dinv) ========
// 64 rows/block, 4 waves, K-step 32, no LDS. mfma_f32_16x16x32_f16:
// A row=l&15,k=8*(l>>4)+j; B packed col=l&15; C/D col=l&15,row=(l>>4)*4+reg.

template <int K, bool AF32>
__global__ __launch_bounds__(256)
void gemm_mfma_kernel(const void* __restrict__ Aptr, const _Float16* __restrict__ Wp,
                      const float* __restrict__ dinv, _Float16* __restrict__ Hs, int N) {
    const int tid = threadIdx.x;
    const int l = tid & 63;
    const int w = tid >> 6;
    const int r0 = blockIdx.x * 64 + w * 16;
    const int arow_ = r0 + (l & 15);
    const int arow = arow_ < N ? arow_ : N - 1;   // clamp; stores guarded
    const int kb = (l >> 4) * 8;

    f32x4 acc[4] = {};
#pragma unroll
    for (int s = 0; s < K / 32; ++s) {
        half8 a;
        if constexpr (AF32) {
            const float* A = (const float*)Aptr;
            const float4 f0 = *reinterpret_cast<const float4*>(&A[(size_t)arow * K + 32 * s + kb]);
            const float4 f1 = *reinterpret_cast<const float4*>(&A[(size_t)arow * K + 32 * s + kb + 4]);
            a[0] = (_Float16)f0.x; a[1] = (_Float16)f0.y;
            a[2] = (_Float16)f0.z; a[3] = (_Float16)f0.w;
            a[4] = (_Float16)f1.x; a[5] = (_Float16)f1.y;
            a[6] = (_Float16)f1.z; a[7] = (_Float16)f1.w;
        } else {
            const _Float16* A = (const _Float16*)Aptr;
            a = *reinterpret_cast<const half8*>(&A[(size_t)arow * K + 32 * s + kb]);
        }
        const half8* Wb = reinterpret_cast<const half8*>(&Wp[(size_t)(s * 4) * 64 * 8]);
#pragma unroll
        for (int g = 0; g < 4; ++g) {
            const half8 b = Wb[g * 64 + l];
            acc[g] = __builtin_amdgcn_mfma_f32_16x16x32_f16(a, b, acc[g], 0, 0, 0);
        }
    }

    const int rb = r0 + (l >> 4) * 4;
    float dv[4];
#pragma unroll
    for (int j = 0; j < 4; ++j) {
        const int r = rb + j;
        dv[j] = dinv[r < N ? r : N - 1];
    }
#pragma unroll
    for (int g = 0; g < 4; ++g) {
#pragma unroll
        for (int j = 0; j < 4; ++j) {
            const int r = rb + j;
            if (r < N)
                Hs[(size_t)r * 64 + g * 16 + (l & 15)] = (_Float16)(acc[g][j] * dv[j]);
        }
    }
}

// ---------------- pull-style aggregation, fused self-term + bias (+ReLU) ----
// 4 nodes per wave: quarter-wave (16 lanes) per node, 4 fp16 feats/lane (8B).

template <bool RELU>
__global__ __launch_bounds__(256)
void gather_kernel(const __half* __restrict__ Hs, const float* __restrict__ dinv,
                   const int* __restrict__ off, const int* __restrict__ srcrow,
                   const float* __restrict__ bias, __half* __restrict__ A, int N) {
    const int tid  = threadIdx.x;
    const int lane = tid & 63;
    const int q    = lane >> 4;              // quarter 0..3 = node sub-id
    const int fl   = (lane & 15) << 2;       // feature base (0,4,...,60)
    const int wid  = tid >> 6;               // wave 0..3
    const int c    = blockIdx.x * 16 + wid * 4 + q;
    const int cc   = (c < N) ? c : N - 1;    // clamp; store is guarded
    const int lo = off[cc], hi = off[cc + 1];

    float4 acc = make_float4(0.f, 0.f, 0.f, 0.f);
    int j = lo;
    while (__any(j < hi)) {
        int idx[8];
#pragma unroll
        for (int u = 0; u < 8; ++u) {
            const int jj = j + u;
            idx[u] = srcrow[jj < hi ? jj : (hi > lo ? hi - 1 : 0)];
        }
        uint2 hv[8];
#pragma unroll
        for (int u = 0; u < 8; ++u)
            hv[u] = *reinterpret_cast<const uint2*>(&Hs[(size_t)idx[u] * 64 + fl]);
#pragma unroll
        for (int u = 0; u < 8; ++u) {
            if (j + u < hi) {
                union { uint2 uu; __half2 h2[2]; } v; v.uu = hv[u];
                const float2 a = __half22float2(v.h2[0]);
                const float2 b = __half22float2(v.h2[1]);
                acc.x += a.x; acc.y += a.y; acc.z += b.x; acc.w += b.y;
            }
        }
        j += 8;
    }

    if (c < N) {
        const float dc = dinv[c];
        union { uint2 uu; __half2 h2[2]; } sv;
        sv.uu = *reinterpret_cast<const uint2*>(&Hs[(size_t)c * 64 + fl]);
        const float2 s0 = __half22float2(sv.h2[0]);
        const float2 s1 = __half22float2(sv.h2[1]);
        const float4 bl = *reinterpret_cast<const float4*>(&bias[fl]);
        float4 o;
        o.x = dc * (acc.x + s0.x) + bl.x;
        o.y = dc * (acc.y + s0.y) + bl.y;
        o.z = dc * (acc.z + s1.x) + bl.z;
        o.w = dc * (acc.w + s1.y) + bl.w;
        if (RELU) {
            o.x = fmaxf(o.x, 0.f); o.y = fmaxf(o.y, 0.f);
            o.z = fmaxf(o.z, 0.f); o.w = fmaxf(o.w, 0.f);
        }
        union { uint2 uu; __half2 h2[2]; } ov;
        ov.h2[0] = __floats2half2_rn(o.x, o.y);
        ov.h2[1] = __floats2half2_rn(o.z, o.w);
        *reinterpret_cast<uint2*>(&A[(size_t)c * 64 + fl]) = ov.uu;
    }
}

// ---------------- mean-pool (batch is sorted) + final linear ----------------

__global__ __launch_bounds__(256)
void pool_kernel(const __half* __restrict__ A, const int* __restrict__ batch,
                 float* __restrict__ pooled, int* __restrict__ gcnt, int N) {
    const int g = blockIdx.x >> 3;
    const int stripe = blockIdx.x & 7;
    int lo = 0, hi = N;
    while (lo < hi) { int m = (lo + hi) >> 1; if (batch[m] < g) lo = m + 1; else hi = m; }
    const int beg = lo;
    lo = beg; hi = N;
    while (lo < hi) { int m = (lo + hi) >> 1; if (batch[m] < g + 1) lo = m + 1; else hi = m; }
    const int end = lo;

    const int lane = threadIdx.x & 63;
    const int wsid = stripe * 4 + (threadIdx.x >> 6);
    float acc = 0.f;
    for (int i = beg + wsid; i < end; i += 32)
        acc += __half2float(A[(size_t)i * 64 + lane]);
    atomicAdd(&pooled[g * 64 + lane], acc);
    if (stripe == 0 && threadIdx.x == 0) gcnt[g] = end - beg;
}

__global__ void final_kernel(const float* __restrict__ pooled, const int* __restrict__ gcnt,
                             const float* __restrict__ Wlin, const float* __restrict__ blin,
                             float* __restrict__ out) {
    const int t = threadIdx.x;
    const int g = t >> 1, o = t & 1;
    const float c = (float)max(gcnt[g], 1);
    float acc = 0.f;
    for (int k = 0; k < 64; ++k)
        acc = fmaf(pooled[g * 64 + k], Wlin[k * 2 + o], acc);
    out[g * 2 + o] = acc / c + blin[o];
}

// ---------------- launch ----------------

extern "C" void kernel_launch(void* const* d_in, const int* in_sizes, int n_in,
                              void* d_out, int out_size, void* d_ws, size_t ws_size,
                              hipStream_t stream) {
    const float* x     = (const float*)d_in[0];
    const int*   ei    = (const int*)d_in[1];
    const int*   batch = (const int*)d_in[2];
    const float* W1    = (const float*)d_in[3];
    const float* b1    = (const float*)d_in[4];
    const float* W2    = (const float*)d_in[5];
    const float* b2    = (const float*)d_in[6];
    const float* W3    = (const float*)d_in[7];
    const float* b3    = (const float*)d_in[8];
    const float* Wlin  = (const float*)d_in[9];
    const float* blin  = (const float*)d_in[10];

    const int N = in_sizes[0] / IN_CH;
    const int E = in_sizes[1] / 2;
    const int* row = ei;
    const int* col = ei + E;
    const int nb = (N + 127) >> 7;   // 128-node buckets (782 for N=100k)

    char* p = (char*)d_ws;
    auto alloc = [&](size_t bytes) {
        char* q = p;
        p += (bytes + 511) & ~(size_t)511;
        return q;
    };
    int*      off    = (int*)alloc((size_t)(N + 1) * 4);
    float*    dinv   = (float*)alloc((size_t)N * 4);
    int*      srcrow = (int*)alloc((size_t)E * 4);
    unsigned* tmp    = (unsigned*)alloc((size_t)E * 4);
    _Float16* Hbuf   = (_Float16*)alloc((size_t)N * HIDDEN * 2);
    _Float16* Abuf   = (_Float16*)alloc((size_t)N * HIDDEN * 2);
    _Float16* Wp1    = (_Float16*)alloc((size_t)IN_CH * 64 * 2);
    _Float16* Wp2    = (_Float16*)alloc((size_t)HIDDEN * 64 * 2);
    _Float16* Wp3    = (_Float16*)alloc((size_t)HIDDEN * 64 * 2);
    int*      bhist  = (int*)alloc(NB * 4);
    int*      bbase  = (int*)alloc((NB + 1) * 4);
    int*      bpos   = (int*)alloc(NB * 4);
    float*    pooled = (float*)alloc(64 * 64 * 4);
    int*      gcnt   = (int*)alloc(64 * 4);
    (void)ws_size; (void)n_in; (void)out_size;

    // --- W repack (3 blocks; block 0 zeroes bhist) ---
    pack3_kernel<<<3, 256, 0, stream>>>(W1, W2, W3, Wp1, Wp2, Wp3, bhist);

    // --- CSR build (bucket sort; also produces dinv + zeroes pooled) ---
    const int eb = (E + 8191) / 8192;
    bucket_hist_kernel<<<eb, 1024, 0, stream>>>(col, bhist, E);
    bucket_scan_kernel<<<1, 1024, 0, stream>>>(bhist, bbase, bpos, off, pooled, N, E);
    bucket_scatter_kernel<<<eb, 1024, 0, stream>>>(row, col, bpos, tmp, E);
    bucket_sort_kernel<<<nb, 256, 0, stream>>>(tmp, bbase, off, dinv, srcrow, N);

    // --- 3 GCN layers ---
    const int gemm_grid   = (N + 63) / 64;
    const int gather_grid = (N + 15) / 16;   // 16 nodes per 256-thread block
    gemm_mfma_kernel<IN_CH, true><<<gemm_grid, 256, 0, stream>>>(x, Wp1, dinv, Hbuf, N);
    gather_kernel<true><<<gather_grid, 256, 0, stream>>>((const __half*)Hbuf, dinv, off, srcrow, b1, (__half*)Abuf, N);
    gemm_mfma_kernel<HIDDEN, false><<<gemm_grid, 256, 0, stream>>>(Abuf, Wp2, dinv, Hbuf, N);
    gather_kernel<true><<<gather_grid, 256, 0, stream>>>((const __half*)Hbuf, dinv, off, srcrow, b2, (__half*)Abuf, N);
    gemm_mfma_kernel<HIDDEN, false><<<gemm_grid, 256, 0, stream>>>(Abuf, Wp3, dinv, Hbuf, N);
    gather_kernel<false><<<gather_grid, 256, 0, stream>>>((const __half*)Hbuf, dinv, off, srcrow, b3, (__half*)Abuf, N);

    // --- mean pool + final linear ---
    pool_kernel<<<512, 256, 0, stream>>>((const __half*)Abuf, batch, pooled, gcnt, N);
    final_kernel<<<1, 128, 0, stream>>>(pooled, gcnt, Wlin, blin, (float*)d_out);
}